// Round 5
// baseline (2793.169 us; speedup 1.0000x reference)
//
#include <hip/hip_runtime.h>
#include <stdint.h>

#define N_NODES 100000
#define N_EDGES 400000
#define N_GRAPHS 2000
#define C_IN 48
#define HD 128
#define NLAYERS 6
#define BN_EPS 1e-5f
#define NSLOPE 0.01f
#define SB 391   // ceil(N_NODES/256)
#define NREP 8   // stats replication factor
#define NTILES 6250
#define KTILES 7 // max tiles per block at grid >= 893

typedef uint16_t u16;
typedef uint32_t u32;
typedef short bf16x8 __attribute__((ext_vector_type(8)));
typedef float f32x4 __attribute__((ext_vector_type(4)));

__device__ __forceinline__ float bf2f_lo(u32 v) { return __uint_as_float(v << 16); }
__device__ __forceinline__ float bf2f_hi(u32 v) { return __uint_as_float(v & 0xffff0000u); }
__device__ __forceinline__ float bf2f(u16 h) { return __uint_as_float(((u32)h) << 16); }
__device__ __forceinline__ u16 f2bf(float f) {
    u32 u = __float_as_uint(f);
    u32 r = (u + 0x7fffu + ((u >> 16) & 1u)) >> 16;
    return (u16)r;
}
__device__ __forceinline__ u32 pack2(float a, float b) {
    return (u32)f2bf(a) | ((u32)f2bf(b) << 16);
}
// lrelu(x) = max(0.01x, x): 2 VALU, branchless, identical values for finite x.
__device__ __forceinline__ float lrelu(float v) { return fmaxf(v * NSLOPE, v); }

// dtype detection: mode=1 -> float inputs are fp32; mode=0 -> bf16.
__global__ __launch_bounds__(256) void detect_kernel(const u16* __restrict__ x, int* __restrict__ mode) {
    __shared__ int flag;
    if (threadIdx.x == 0) flag = 0;
    __syncthreads();
    int local = 0;
    for (int i = threadIdx.x; i < 16384; i += 256) {
        float a = fabsf(bf2f(x[i]));
        if (!(a < 1e4f)) local = 1;
    }
    if (local) flag = 1;
    __syncthreads();
    if (threadIdx.x == 0) mode[0] = flag;
}

// ---------------- x -> padded bf16 rows (one 128B cache line per row) ----------------
__global__ __launch_bounds__(256) void convx_kernel(const void* __restrict__ xv, const int* __restrict__ mode,
                                                    u16* __restrict__ xb) {
    const int gid = blockIdx.x * 256 + threadIdx.x;  // 6250*256 == N_NODES*16 exactly
    const int row = gid >> 4, part = gid & 15;       // part = 4 cols
    u16 o0 = 0, o1 = 0, o2 = 0, o3 = 0;
    if (part < 12) {
        if (*mode) {
            const float4 v = *reinterpret_cast<const float4*>((const float*)xv + (size_t)row * C_IN + part * 4);
            o0 = f2bf(v.x); o1 = f2bf(v.y); o2 = f2bf(v.z); o3 = f2bf(v.w);
        } else {
            const ushort4 v = *reinterpret_cast<const ushort4*>((const u16*)xv + (size_t)row * C_IN + part * 4);
            o0 = v.x; o1 = v.y; o2 = v.z; o3 = v.w;
        }
    }
    ushort4 o; o.x = o0; o.y = o1; o.z = o2; o.w = o3;
    *reinterpret_cast<ushort4*>(xb + (size_t)row * 64 + part * 4) = o;
}

// ---------------- CSR build ----------------
__global__ __launch_bounds__(256) void hist_kernel(const int* __restrict__ dst, int* __restrict__ cnt) {
    int e = blockIdx.x * 256 + threadIdx.x;
    if (e < N_EDGES) atomicAdd(&cnt[dst[e]], 1);
}

__global__ __launch_bounds__(256) void scan1_kernel(const int* __restrict__ cnt, int* __restrict__ bsum) {
    __shared__ int s[256];
    const int t = threadIdx.x;
    const int i = blockIdx.x * 256 + t;
    s[t] = (i < N_NODES) ? cnt[i] : 0;
    __syncthreads();
    for (int d = 128; d > 0; d >>= 1) {
        if (t < d) s[t] += s[t + d];
        __syncthreads();
    }
    if (t == 0) bsum[blockIdx.x] = s[0];
}

__global__ __launch_bounds__(512) void scan2_kernel(int* __restrict__ bsum, int* __restrict__ row_ptr) {
    __shared__ int s[SB];
    const int t = threadIdx.x;
    if (t < SB) s[t] = bsum[t];
    __syncthreads();
    if (t == 0) {
        int run = 0;
        for (int b = 0; b < SB; ++b) { int v = s[b]; s[b] = run; run += v; }
        row_ptr[0] = 0;
    }
    __syncthreads();
    if (t < SB) bsum[t] = s[t];
}

// also writes cursor[i] = row_ptr[i] (exclusive prefix) -> drops the memcpy node
__global__ __launch_bounds__(256) void scan3_kernel(const int* __restrict__ cnt, const int* __restrict__ bsum,
                                                    int* __restrict__ row_ptr, int* __restrict__ cursor) {
    __shared__ int s[256];
    const int t = threadIdx.x;
    const int i = blockIdx.x * 256 + t;
    const int myc = (i < N_NODES) ? cnt[i] : 0;
    s[t] = myc;
    __syncthreads();
    if (t == 0) {
        int run = bsum[blockIdx.x];
        for (int j = 0; j < 256; ++j) { run += s[j]; s[j] = run; }
    }
    __syncthreads();
    if (i < N_NODES) {
        row_ptr[i + 1] = s[t];
        cursor[i] = s[t] - myc;
    }
}

__global__ __launch_bounds__(256) void fill_kernel(const int* __restrict__ src, const int* __restrict__ dst,
                                                   int* __restrict__ cursor, int* __restrict__ col_idx) {
    int e = blockIdx.x * 256 + threadIdx.x;
    if (e < N_EDGES) {
        int d = dst[e];
        int slot = atomicAdd(&cursor[d], 1);
        col_idx[slot] = src[e];
    }
}

// ---------------- weight pre-pack into MFMA B-fragment layout (bf16) ----------------
__global__ __launch_bounds__(256) void pack_w_kernel(const void* __restrict__ W1a, const void* __restrict__ W1b,
                                                     const void* __restrict__ W2, const int* __restrict__ mode,
                                                     u16* __restrict__ wpack) {
    const int t = blockIdx.x * 256 + threadIdx.x;  // 12*2048 = 24576
    if (t >= 24576) return;
    const int mat = t >> 11;
    const int r = t & 2047;
    const int l = r & 63;
    const int f = r >> 6;
    const int kb = f >> 3, nt = f & 7;
    const int k0 = kb * 32 + (l >> 4) * 8;
    const int n = nt * 16 + (l & 15);
    const int md = *mode;
    u16 vals[8];
    #pragma unroll
    for (int j = 0; j < 8; ++j) {
        const int k = k0 + j;
        float v;
        if (mat == 0) {
            v = (k < C_IN) ? (md ? ((const float*)W1a)[k * HD + n] : bf2f(((const u16*)W1a)[k * HD + n])) : 0.f;
        } else if (mat < 6) {
            const size_t o = (size_t)(mat - 1) * HD * HD + (size_t)k * HD + n;
            v = md ? ((const float*)W1b)[o] : bf2f(((const u16*)W1b)[o]);
        } else {
            const size_t o = (size_t)(mat - 6) * HD * HD + (size_t)k * HD + n;
            v = md ? ((const float*)W2)[o] : bf2f(((const u16*)W2)[o]);
        }
        vals[j] = f2bf(v);
    }
    uint4 o;
    o.x = (u32)vals[0] | ((u32)vals[1] << 16);
    o.y = (u32)vals[2] | ((u32)vals[3] << 16);
    o.z = (u32)vals[4] | ((u32)vals[5] << 16);
    o.w = (u32)vals[6] | ((u32)vals[7] << 16);
    *reinterpret_cast<uint4*>(wpack + (size_t)t * 8) = o;
}

// ---------------- bias pre-pack to f32 ----------------
__global__ __launch_bounds__(256) void pack_b_kernel(const void* __restrict__ b1, const void* __restrict__ b2,
                                                     const int* __restrict__ mode, float* __restrict__ biasf) {
    const int i = blockIdx.x * 256 + threadIdx.x;  // 12*128
    if (i >= 12 * HD) return;
    const int mat = i >> 7, c = i & 127;
    const int md = *mode;
    float v;
    if (mat < 6) v = md ? ((const float*)b1)[mat * HD + c] : bf2f(((const u16*)b1)[mat * HD + c]);
    else         v = md ? ((const float*)b2)[(mat - 6) * HD + c] : bf2f(((const u16*)b2)[(mat - 6) * HD + c]);
    biasf[i] = v;
}

// ---- shared helper: compute BN coef[256]={A,B} in LDS from replicated raw stats ----
__device__ __forceinline__ void coef_to_lds(float* coefs, const float* __restrict__ instats,
                                            const void* __restrict__ gammav, const void* __restrict__ betav,
                                            size_t gelem, int md, int tid) {
    if (tid < 128) {
        float sm = 0.f, sq = 0.f;
        #pragma unroll
        for (int rep = 0; rep < NREP; ++rep) {
            sm += instats[rep * 256 + tid];
            sq += instats[rep * 256 + 128 + tid];
        }
        const float inv_n = 1.0f / (float)N_NODES;
        const float mean = sm * inv_n;
        const float var = fmaxf(sq * inv_n - mean * mean, 0.f);
        const float rs = rsqrtf(var + BN_EPS);
        const float g  = md ? ((const float*)gammav)[gelem + tid] : bf2f(((const u16*)gammav)[gelem + tid]);
        const float be = md ? ((const float*)betav)[gelem + tid]  : bf2f(((const u16*)betav)[gelem + tid]);
        const float A = g * rs;
        coefs[tid] = A;
        coefs[128 + tid] = be - A * mean;
    }
}

// ---------------- grid barrier (device-scope, monotonic counter) ----------------
// Correct iff all blocks co-resident: grid = 4 blocks/CU with 36KB LDS + VGPR<=128 (launch_bounds)
// guarantees exactly 4/CU fit. __threadfence emits the agent-scope L2 writeback/invalidate that a
// kernel boundary would otherwise provide (per-XCD L2s are not coherent).
__device__ __forceinline__ void grid_barrier(int* bar, int target) {
    __syncthreads();
    if (threadIdx.x == 0) {
        __threadfence();
        __hip_atomic_fetch_add(bar, 1, __ATOMIC_RELEASE, __HIP_MEMORY_SCOPE_AGENT);
        while (__hip_atomic_load(bar, __ATOMIC_ACQUIRE, __HIP_MEMORY_SCOPE_AGENT) < target)
            __builtin_amdgcn_s_sleep(2);
        __threadfence();
    }
    __syncthreads();
}

// ================= PERSISTENT FUSED 6-LAYER KERNEL =================
// Per layer: phase A = gather(+prev outer BN)+lin1 -> t kept in LDS (tstore), stats->statsA;
// grid barrier; phase B = inner BN (in LDS) + lin2 -> h' global, stats->statsB; grid barrier.
// t NEVER round-trips through global memory; 12 kernel launches -> 1.
__global__ __launch_bounds__(256, 4) void layers_fused(
        const u16* __restrict__ xb, u16* __restrict__ zb, u16* __restrict__ hb,
        const int* __restrict__ row_ptr, const int* __restrict__ col_idx,
        const u16* __restrict__ wpack, const float* __restrict__ biasf,
        const void* __restrict__ g1v, const void* __restrict__ be1v,
        const void* __restrict__ gnv, const void* __restrict__ bnbv,
        const int* __restrict__ mode, float* __restrict__ statsAll,
        int* __restrict__ bar) {
    __shared__ u16 tstore[KTILES][16][136];  // 30464 B
    __shared__ u16 Asm[16][136];             // 4352 B
    __shared__ float coefs[256];             // 1024 B
    __shared__ float sred[128];              // 512 B
    __shared__ float sqred[128];             // 512 B   => 36864 B total (4 blocks/CU)

    const int tid = threadIdx.x;
    const int rrow = tid >> 4, seg = tid & 15;
    const int wave = tid >> 6, lane = tid & 63;
    const int quad = lane >> 4, lx = lane & 15;
    const int md = *mode;
    const int nrepslot = blockIdx.x & (NREP - 1);
    const int G = (int)gridDim.x;
    int btgt = 0;

    for (int l = 0; l < NLAYERS; ++l) {
        const u16* inb = (l == 0) ? xb : (((l - 1) & 1) ? hb : zb);
        u16* outb = (l & 1) ? hb : zb;
        const u16* wp1 = wpack + (size_t)l * HD * HD;
        const u16* wp2 = wpack + (size_t)(6 + l) * HD * HD;
        const float* b1f = biasf + l * HD;
        const float* b2f = biasf + (6 + l) * HD;
        float* statsA = statsAll + (size_t)l * NREP * 256;
        float* statsB = statsAll + (size_t)(6 + l) * NREP * 256;

        // ===== phase A: gather(+outer BN l-1)+lin1 -> tstore =====
        if (tid < 128) { sred[tid] = 0.f; sqred[tid] = 0.f; }
        if (l > 0)
            coef_to_lds(coefs, statsAll + (size_t)(5 + l) * NREP * 256, gnv, bnbv,
                        (size_t)(l - 1) * HD, md, tid);
        __syncthreads();
        float cA[8], cB[8];
        if (l > 0) {
            #pragma unroll
            for (int j = 0; j < 8; ++j) { cA[j] = coefs[seg * 8 + j]; cB[j] = coefs[128 + seg * 8 + j]; }
        }
        for (int ti = 0; ti < KTILES; ++ti) {
            const int tile = blockIdx.x + ti * G;
            if (tile >= NTILES) break;   // uniform per block
            const int gm = tile * 16 + rrow;
            {
                float a[8];
                #pragma unroll
                for (int j = 0; j < 8; ++j) a[j] = 0.f;
                if (l == 0) {
                    if (seg < 8) {  // xb: 64 padded cols, 128B line-aligned rows
                        const u32 soff = (u32)seg << 4;
                        {
                            const uint4 v = *reinterpret_cast<const uint4*>((const char*)xb + (((u32)gm << 7) + soff));
                            const u32 w[4] = {v.x, v.y, v.z, v.w};
                            #pragma unroll
                            for (int p = 0; p < 4; ++p) { a[2 * p] = bf2f_lo(w[p]); a[2 * p + 1] = bf2f_hi(w[p]); }
                        }
                        const int s0 = row_ptr[gm];
                        const int deg = row_ptr[gm + 1] - s0;
                        for (int e = 0; e < deg; e += 2) {
                            const int id0 = col_idx[s0 + e];
                            const bool h1 = (e + 1) < deg;
                            const int id1 = h1 ? col_idx[s0 + e + 1] : 0;
                            const uint4 r0 = *reinterpret_cast<const uint4*>((const char*)xb + (((u32)id0 << 7) + soff));
                            uint4 r1; r1.x = r1.y = r1.z = r1.w = 0;
                            if (h1) r1 = *reinterpret_cast<const uint4*>((const char*)xb + (((u32)id1 << 7) + soff));
                            const u32 w0[4] = {r0.x, r0.y, r0.z, r0.w};
                            const u32 w1[4] = {r1.x, r1.y, r1.z, r1.w};
                            #pragma unroll
                            for (int p = 0; p < 4; ++p) {
                                a[2 * p]     += bf2f_lo(w0[p]) + bf2f_lo(w1[p]);
                                a[2 * p + 1] += bf2f_hi(w0[p]) + bf2f_hi(w1[p]);
                            }
                        }
                    }
                } else {
                    const u32 soff = (u32)seg << 4;
                    {
                        const uint4 v = *reinterpret_cast<const uint4*>((const char*)inb + (((u32)gm << 8) + soff));
                        const u32 w[4] = {v.x, v.y, v.z, v.w};
                        #pragma unroll
                        for (int p = 0; p < 4; ++p) {
                            a[2 * p]     = lrelu(cA[2 * p] * bf2f_lo(w[p]) + cB[2 * p]);
                            a[2 * p + 1] = lrelu(cA[2 * p + 1] * bf2f_hi(w[p]) + cB[2 * p + 1]);
                        }
                    }
                    const int s0 = row_ptr[gm];
                    const int deg = row_ptr[gm + 1] - s0;
                    for (int e = 0; e < deg; e += 2) {
                        const int id0 = col_idx[s0 + e];
                        const bool h1 = (e + 1) < deg;
                        const int id1 = h1 ? col_idx[s0 + e + 1] : 0;
                        const uint4 r0 = *reinterpret_cast<const uint4*>((const char*)inb + (((u32)id0 << 8) + soff));
                        uint4 r1; r1.x = r1.y = r1.z = r1.w = 0;
                        if (h1) r1 = *reinterpret_cast<const uint4*>((const char*)inb + (((u32)id1 << 8) + soff));
                        const u32 w0[4] = {r0.x, r0.y, r0.z, r0.w};
                        const u32 w1[4] = {r1.x, r1.y, r1.z, r1.w};
                        #pragma unroll
                        for (int p = 0; p < 4; ++p) {
                            a[2 * p]     += lrelu(cA[2 * p] * bf2f_lo(w0[p]) + cB[2 * p]);
                            a[2 * p + 1] += lrelu(cA[2 * p + 1] * bf2f_hi(w0[p]) + cB[2 * p + 1]);
                            if (h1) {
                                a[2 * p]     += lrelu(cA[2 * p] * bf2f_lo(w1[p]) + cB[2 * p]);
                                a[2 * p + 1] += lrelu(cA[2 * p + 1] * bf2f_hi(w1[p]) + cB[2 * p + 1]);
                            }
                        }
                    }
                }
                uint4 o;
                o.x = pack2(a[0], a[1]); o.y = pack2(a[2], a[3]);
                o.z = pack2(a[4], a[5]); o.w = pack2(a[6], a[7]);
                *reinterpret_cast<uint4*>(&Asm[rrow][seg * 8]) = o;
            }
            __syncthreads();
            f32x4 acc[2] = {};
            const int kbn = (l == 0) ? 2 : 4;   // layer-0: K=64..127 all-zero, skip
            for (int kb = 0; kb < kbn; ++kb) {
                bf16x8 bfr[2];
                #pragma unroll
                for (int nt = 0; nt < 2; ++nt)
                    bfr[nt] = *reinterpret_cast<const bf16x8*>(wp1 + (((size_t)(kb * 8 + wave * 2 + nt) * 64 + lane) << 3));
                const bf16x8 af = *reinterpret_cast<const bf16x8*>(&Asm[lx][kb * 32 + quad * 8]);
                #pragma unroll
                for (int nt = 0; nt < 2; ++nt)
                    acc[nt] = __builtin_amdgcn_mfma_f32_16x16x32_bf16(af, bfr[nt], acc[nt], 0, 0, 0);
            }
            __syncthreads();   // Asm free for next tile
            #pragma unroll
            for (int nt = 0; nt < 2; ++nt) {
                const int n = wave * 32 + nt * 16 + lx;
                const float bj = b1f[n];
                float s = 0.f, q = 0.f;
                #pragma unroll
                for (int r = 0; r < 4; ++r) {
                    const float v = acc[nt][r] + bj;
                    tstore[ti][quad * 4 + r][n] = f2bf(v);
                    s += v; q += v * v;
                }
                s += __shfl_xor(s, 16); s += __shfl_xor(s, 32);
                q += __shfl_xor(q, 16); q += __shfl_xor(q, 32);
                if (quad == 0) { sred[n] += s; sqred[n] += q; }  // same lane accumulates across tiles
            }
        }
        __syncthreads();
        {
            float* sdst = statsA + (size_t)nrepslot * 256;
            if (tid < 128) atomicAdd(&sdst[tid], sred[tid]);
            else           atomicAdd(&sdst[tid], sqred[tid - 128]);
        }
        btgt += G;
        grid_barrier(bar, btgt);

        // ===== phase B: inner BN (in LDS) + lin2 -> outb =====
        if (tid < 128) { sred[tid] = 0.f; sqred[tid] = 0.f; }
        coef_to_lds(coefs, statsA, g1v, be1v, (size_t)l * HD, md, tid);
        __syncthreads();
        #pragma unroll
        for (int j = 0; j < 8; ++j) { cA[j] = coefs[seg * 8 + j]; cB[j] = coefs[128 + seg * 8 + j]; }
        for (int ti = 0; ti < KTILES; ++ti) {
            const int tile = blockIdx.x + ti * G;
            if (tile >= NTILES) break;
            {   // BN+lrelu in place on tstore[ti]
                uint4 o = *reinterpret_cast<const uint4*>(&tstore[ti][rrow][seg * 8]);
                u32 w[4] = {o.x, o.y, o.z, o.w};
                #pragma unroll
                for (int p = 0; p < 4; ++p) {
                    const float lo = lrelu(cA[2 * p] * bf2f_lo(w[p]) + cB[2 * p]);
                    const float hi = lrelu(cA[2 * p + 1] * bf2f_hi(w[p]) + cB[2 * p + 1]);
                    w[p] = pack2(lo, hi);
                }
                o.x = w[0]; o.y = w[1]; o.z = w[2]; o.w = w[3];
                *reinterpret_cast<uint4*>(&tstore[ti][rrow][seg * 8]) = o;
            }
            __syncthreads();
            f32x4 acc[2] = {};
            #pragma unroll
            for (int kb = 0; kb < 4; ++kb) {
                bf16x8 bfr[2];
                #pragma unroll
                for (int nt = 0; nt < 2; ++nt)
                    bfr[nt] = *reinterpret_cast<const bf16x8*>(wp2 + (((size_t)(kb * 8 + wave * 2 + nt) * 64 + lane) << 3));
                const bf16x8 af = *reinterpret_cast<const bf16x8*>(&tstore[ti][lx][kb * 32 + quad * 8]);
                #pragma unroll
                for (int nt = 0; nt < 2; ++nt)
                    acc[nt] = __builtin_amdgcn_mfma_f32_16x16x32_bf16(af, bfr[nt], acc[nt], 0, 0, 0);
            }
            const int m0 = tile * 16;
            #pragma unroll
            for (int nt = 0; nt < 2; ++nt) {
                const int n = wave * 32 + nt * 16 + lx;
                const float bj = b2f[n];
                float s = 0.f, q = 0.f;
                #pragma unroll
                for (int r = 0; r < 4; ++r) {
                    const int m = m0 + quad * 4 + r;
                    const float v = acc[nt][r] + bj;
                    outb[(size_t)m * HD + n] = f2bf(v);
                    s += v; q += v * v;
                }
                if (l < NLAYERS - 1) {
                    s += __shfl_xor(s, 16); s += __shfl_xor(s, 32);
                    q += __shfl_xor(q, 16); q += __shfl_xor(q, 32);
                    if (quad == 0) { sred[n] += s; sqred[n] += q; }
                }
            }
            // no sync needed: next tile touches a different tstore slot
        }
        if (l < NLAYERS - 1) {
            __syncthreads();
            float* sdst = statsB + (size_t)nrepslot * 256;
            if (tid < 128) atomicAdd(&sdst[tid], sred[tid]);
            else           atomicAdd(&sdst[tid], sqred[tid - 128]);
            btgt += G;
            grid_barrier(bar, btgt);
        }
    }
}

// ================= FALLBACK PATH (round-4 kernels, used if co-residency can't be guaranteed) =================
template <int TRANS, int STATS>
__global__ __launch_bounds__(256) void gemm_mfma(const u16* A, const u16* __restrict__ wp,
                                                 const float* __restrict__ biasf,
                                                 const float* __restrict__ instats,
                                                 const void* __restrict__ gammav, const void* __restrict__ betav,
                                                 size_t gelem, const int* __restrict__ mode,
                                                 u16* out, float* __restrict__ stats) {
    __shared__ u16 Asm[16][136];
    __shared__ float sred[128];
    __shared__ float sqred[128];
    __shared__ float coefs[256];
    const int tid = threadIdx.x;
    const int m0 = blockIdx.x * 16;
    const int rrow = tid >> 4;
    const int seg = tid & 15;

    if (TRANS) {
        coef_to_lds(coefs, instats, gammav, betav, gelem, *mode, tid);
        __syncthreads();
    }
    {
        const int gm = m0 + rrow;
        uint4 o = *reinterpret_cast<const uint4*>((const char*)A + (((u32)gm << 8) + ((u32)seg << 4)));
        if (TRANS) {
            float cA[8], cB[8];
            #pragma unroll
            for (int j = 0; j < 8; ++j) { cA[j] = coefs[seg * 8 + j]; cB[j] = coefs[128 + seg * 8 + j]; }
            u32 w[4] = {o.x, o.y, o.z, o.w};
            #pragma unroll
            for (int p = 0; p < 4; ++p) {
                const float lo = lrelu(cA[2 * p] * bf2f_lo(w[p]) + cB[2 * p]);
                const float hi = lrelu(cA[2 * p + 1] * bf2f_hi(w[p]) + cB[2 * p + 1]);
                w[p] = pack2(lo, hi);
            }
            o.x = w[0]; o.y = w[1]; o.z = w[2]; o.w = w[3];
        }
        *reinterpret_cast<uint4*>(&Asm[rrow][seg * 8]) = o;
    }
    __syncthreads();
    const int wave = tid >> 6, lane = tid & 63;
    const int quad = lane >> 4, lx = lane & 15;
    f32x4 acc[2] = {};
    #pragma unroll
    for (int kb = 0; kb < 4; ++kb) {
        bf16x8 bfr[2];
        #pragma unroll
        for (int nt = 0; nt < 2; ++nt)
            bfr[nt] = *reinterpret_cast<const bf16x8*>(wp + (((size_t)(kb * 8 + wave * 2 + nt) * 64 + lane) << 3));
        const bf16x8 af = *reinterpret_cast<const bf16x8*>(&Asm[lx][kb * 32 + quad * 8]);
        #pragma unroll
        for (int nt = 0; nt < 2; ++nt)
            acc[nt] = __builtin_amdgcn_mfma_f32_16x16x32_bf16(af, bfr[nt], acc[nt], 0, 0, 0);
    }
    #pragma unroll
    for (int nt = 0; nt < 2; ++nt) {
        const int n = wave * 32 + nt * 16 + lx;
        const float bj = biasf[n];
        float s = 0.f, q = 0.f;
        #pragma unroll
        for (int r = 0; r < 4; ++r) {
            const int m = m0 + quad * 4 + r;
            const float v = acc[nt][r] + bj;
            out[(size_t)m * HD + n] = f2bf(v);
            if (STATS) { s += v; q += v * v; }
        }
        if (STATS) {
            s += __shfl_xor(s, 16); s += __shfl_xor(s, 32);
            q += __shfl_xor(q, 16); q += __shfl_xor(q, 32);
            if (quad == 0) { sred[n] = s; sqred[n] = q; }
        }
    }
    if (STATS) {
        __syncthreads();
        float* sdst = stats + (size_t)(blockIdx.x & (NREP - 1)) * 256;
        if (tid < 128) atomicAdd(&sdst[tid], sred[tid]);
        else if (tid < 256) atomicAdd(&sdst[tid], sqred[tid - 128]);
    }
}

__global__ __launch_bounds__(256) void gemm_gather(const u16* __restrict__ U, const int* __restrict__ row_ptr,
                                                   const int* __restrict__ col_idx, const u16* __restrict__ wp,
                                                   const float* __restrict__ biasf,
                                                   const float* __restrict__ instats,
                                                   const void* __restrict__ gammav, const void* __restrict__ betav,
                                                   size_t gelem, const int* __restrict__ mode,
                                                   u16* __restrict__ out, float* __restrict__ stats) {
    __shared__ u16 Asm[16][136];
    __shared__ float sred[128];
    __shared__ float sqred[128];
    __shared__ float coefs[256];
    const int tid = threadIdx.x;
    const int m0 = blockIdx.x * 16;
    const int rrow = tid >> 4;
    const int seg = tid & 15;

    coef_to_lds(coefs, instats, gammav, betav, gelem, *mode, tid);
    __syncthreads();
    {
        float cA[8], cB[8];
        #pragma unroll
        for (int j = 0; j < 8; ++j) { cA[j] = coefs[seg * 8 + j]; cB[j] = coefs[128 + seg * 8 + j]; }
        const int gm = m0 + rrow;
        const u32 soff = (u32)seg << 4;
        float a[8];
        #pragma unroll
        for (int j = 0; j < 8; ++j) a[j] = 0.f;
        {
            const uint4 v = *reinterpret_cast<const uint4*>((const char*)U + (((u32)gm << 8) + soff));
            const u32 w[4] = {v.x, v.y, v.z, v.w};
            #pragma unroll
            for (int p = 0; p < 4; ++p) {
                a[2 * p]     = lrelu(cA[2 * p] * bf2f_lo(w[p]) + cB[2 * p]);
                a[2 * p + 1] = lrelu(cA[2 * p + 1] * bf2f_hi(w[p]) + cB[2 * p + 1]);
            }
            const int s = row_ptr[gm];
            const int deg = row_ptr[gm + 1] - s;
            for (int t = 0; t < deg; t += 2) {
                const int id0 = col_idx[s + t];
                const bool h1 = (t + 1) < deg;
                const int id1 = h1 ? col_idx[s + t + 1] : 0;
                const uint4 r0 = *reinterpret_cast<const uint4*>((const char*)U + (((u32)id0 << 8) + soff));
                uint4 r1; r1.x = r1.y = r1.z = r1.w = 0;
                if (h1) r1 = *reinterpret_cast<const uint4*>((const char*)U + (((u32)id1 << 8) + soff));
                const u32 w0[4] = {r0.x, r0.y, r0.z, r0.w};
                const u32 w1[4] = {r1.x, r1.y, r1.z, r1.w};
                #pragma unroll
                for (int p = 0; p < 4; ++p) {
                    a[2 * p]     += lrelu(cA[2 * p] * bf2f_lo(w0[p]) + cB[2 * p]);
                    a[2 * p + 1] += lrelu(cA[2 * p + 1] * bf2f_hi(w0[p]) + cB[2 * p + 1]);
                    if (h1) {
                        a[2 * p]     += lrelu(cA[2 * p] * bf2f_lo(w1[p]) + cB[2 * p]);
                        a[2 * p + 1] += lrelu(cA[2 * p + 1] * bf2f_hi(w1[p]) + cB[2 * p + 1]);
                    }
                }
            }
        }
        uint4 o;
        o.x = pack2(a[0], a[1]); o.y = pack2(a[2], a[3]);
        o.z = pack2(a[4], a[5]); o.w = pack2(a[6], a[7]);
        *reinterpret_cast<uint4*>(&Asm[rrow][seg * 8]) = o;
    }
    __syncthreads();
    const int wave = tid >> 6, lane = tid & 63;
    const int quad = lane >> 4, lx = lane & 15;
    f32x4 acc[2] = {};
    #pragma unroll
    for (int kb = 0; kb < 4; ++kb) {
        bf16x8 bfr[2];
        #pragma unroll
        for (int nt = 0; nt < 2; ++nt)
            bfr[nt] = *reinterpret_cast<const bf16x8*>(wp + (((size_t)(kb * 8 + wave * 2 + nt) * 64 + lane) << 3));
        const bf16x8 af = *reinterpret_cast<const bf16x8*>(&Asm[lx][kb * 32 + quad * 8]);
        #pragma unroll
        for (int nt = 0; nt < 2; ++nt)
            acc[nt] = __builtin_amdgcn_mfma_f32_16x16x32_bf16(af, bfr[nt], acc[nt], 0, 0, 0);
    }
    #pragma unroll
    for (int nt = 0; nt < 2; ++nt) {
        const int n = wave * 32 + nt * 16 + lx;
        const float bj = biasf[n];
        float s = 0.f, q = 0.f;
        #pragma unroll
        for (int r = 0; r < 4; ++r) {
            const int m = m0 + quad * 4 + r;
            const float v = acc[nt][r] + bj;
            out[(size_t)m * HD + n] = f2bf(v);
            s += v; q += v * v;
        }
        s += __shfl_xor(s, 16); s += __shfl_xor(s, 32);
        q += __shfl_xor(q, 16); q += __shfl_xor(q, 32);
        if (quad == 0) { sred[n] = s; sqred[n] = q; }
    }
    __syncthreads();
    float* sdst = stats + (size_t)(blockIdx.x & (NREP - 1)) * 256;
    if (tid < 128) atomicAdd(&sdst[tid], sred[tid]);
    else if (tid < 256) atomicAdd(&sdst[tid], sqred[tid - 128]);
}

__global__ __launch_bounds__(256) void gemm_gather0(const u16* __restrict__ xb, const int* __restrict__ row_ptr,
                                                    const int* __restrict__ col_idx, const u16* __restrict__ wp,
                                                    const float* __restrict__ biasf,
                                                    u16* __restrict__ out, float* __restrict__ stats) {
    __shared__ u16 Asm[16][136];
    __shared__ float sred[128];
    __shared__ float sqred[128];
    const int tid = threadIdx.x;
    const int m0 = blockIdx.x * 16;
    const int rrow = tid >> 4;
    const int seg = tid & 15;
    const bool act = seg < 8;
    {
        const int gm = m0 + rrow;
        float a[8];
        #pragma unroll
        for (int j = 0; j < 8; ++j) a[j] = 0.f;
        if (act) {
            const u32 soff = (u32)seg << 4;
            {
                const uint4 v = *reinterpret_cast<const uint4*>((const char*)xb + (((u32)gm << 7) + soff));
                const u32 w[4] = {v.x, v.y, v.z, v.w};
                #pragma unroll
                for (int p = 0; p < 4; ++p) { a[2 * p] = bf2f_lo(w[p]); a[2 * p + 1] = bf2f_hi(w[p]); }
            }
            const int s = row_ptr[gm];
            const int deg = row_ptr[gm + 1] - s;
            for (int t = 0; t < deg; t += 2) {
                const int id0 = col_idx[s + t];
                const bool h1 = (t + 1) < deg;
                const int id1 = h1 ? col_idx[s + t + 1] : 0;
                const uint4 r0 = *reinterpret_cast<const uint4*>((const char*)xb + (((u32)id0 << 7) + soff));
                uint4 r1; r1.x = r1.y = r1.z = r1.w = 0;
                if (h1) r1 = *reinterpret_cast<const uint4*>((const char*)xb + (((u32)id1 << 7) + soff));
                const u32 w0[4] = {r0.x, r0.y, r0.z, r0.w};
                const u32 w1[4] = {r1.x, r1.y, r1.z, r1.w};
                #pragma unroll
                for (int p = 0; p < 4; ++p) {
                    a[2 * p]     += bf2f_lo(w0[p]) + bf2f_lo(w1[p]);
                    a[2 * p + 1] += bf2f_hi(w0[p]) + bf2f_hi(w1[p]);
                }
            }
        }
        uint4 o;
        o.x = pack2(a[0], a[1]); o.y = pack2(a[2], a[3]);
        o.z = pack2(a[4], a[5]); o.w = pack2(a[6], a[7]);
        *reinterpret_cast<uint4*>(&Asm[rrow][seg * 8]) = o;
    }
    __syncthreads();
    const int wave = tid >> 6, lane = tid & 63;
    const int quad = lane >> 4, lx = lane & 15;
    f32x4 acc[2] = {};
    #pragma unroll
    for (int kb = 0; kb < 2; ++kb) {
        bf16x8 bfr[2];
        #pragma unroll
        for (int nt = 0; nt < 2; ++nt)
            bfr[nt] = *reinterpret_cast<const bf16x8*>(wp + (((size_t)(kb * 8 + wave * 2 + nt) * 64 + lane) << 3));
        const bf16x8 af = *reinterpret_cast<const bf16x8*>(&Asm[lx][kb * 32 + quad * 8]);
        #pragma unroll
        for (int nt = 0; nt < 2; ++nt)
            acc[nt] = __builtin_amdgcn_mfma_f32_16x16x32_bf16(af, bfr[nt], acc[nt], 0, 0, 0);
    }
    #pragma unroll
    for (int nt = 0; nt < 2; ++nt) {
        const int n = wave * 32 + nt * 16 + lx;
        const float bj = biasf[n];
        float s = 0.f, q = 0.f;
        #pragma unroll
        for (int r = 0; r < 4; ++r) {
            const int m = m0 + quad * 4 + r;
            const float v = acc[nt][r] + bj;
            out[(size_t)m * HD + n] = f2bf(v);
            s += v; q += v * v;
        }
        s += __shfl_xor(s, 16); s += __shfl_xor(s, 32);
        q += __shfl_xor(q, 16); q += __shfl_xor(q, 32);
        if (quad == 0) { sred[n] = s; sqred[n] = q; }
    }
    __syncthreads();
    float* sdst = stats + (size_t)(blockIdx.x & (NREP - 1)) * 256;
    if (tid < 128) atomicAdd(&sdst[tid], sred[tid]);
    else if (tid < 256) atomicAdd(&sdst[tid], sqred[tid - 128]);
}

// ---------------- merged pooling + classifier head: 500 blocks, wave per graph ----------------
__global__ __launch_bounds__(256) void poolfinal_kernel(const u16* __restrict__ hf, const int* __restrict__ batch,
                                                        const int* __restrict__ mode,
                                                        const void* __restrict__ fcwv, const void* __restrict__ fcbv,
                                                        const void* __restrict__ fc2wv, const void* __restrict__ fc2bv,
                                                        void* __restrict__ outv) {
    __shared__ float embs[4][256];
    __shared__ float hs[4][64];
    const int wave = threadIdx.x >> 6, lane = threadIdx.x & 63;
    const int g = blockIdx.x * 4 + wave;   // 500*4 == N_GRAPHS exactly
    const int md = *mode;
    const int quad = lane >> 4, c = lane & 15;
    int lo = 0, hi = N_NODES;
    while (lo < hi) { int m = (lo + hi) >> 1; if (batch[m] < g) lo = m + 1; else hi = m; }
    const int s = lo;
    hi = N_NODES;
    while (lo < hi) { int m = (lo + hi) >> 1; if (batch[m] < g + 1) lo = m + 1; else hi = m; }
    const int e = lo;
    const int cnt = e - s;
    float sum[8], mx[8];
    #pragma unroll
    for (int j = 0; j < 8; ++j) { sum[j] = 0.f; mx[j] = -INFINITY; }
    for (int n = s + quad; n < e; n += 4) {
        const uint4 v = *reinterpret_cast<const uint4*>(hf + (size_t)n * HD + c * 8);
        const u32 w[4] = {v.x, v.y, v.z, v.w};
        #pragma unroll
        for (int p = 0; p < 4; ++p) {
            const float f0 = bf2f_lo(w[p]), f1 = bf2f_hi(w[p]);
            sum[2 * p] += f0; sum[2 * p + 1] += f1;
            mx[2 * p] = fmaxf(mx[2 * p], f0); mx[2 * p + 1] = fmaxf(mx[2 * p + 1], f1);
        }
    }
    #pragma unroll
    for (int j = 0; j < 8; ++j) {
        sum[j] += __shfl_xor(sum[j], 16); sum[j] += __shfl_xor(sum[j], 32);
        mx[j] = fmaxf(mx[j], __shfl_xor(mx[j], 16));
        mx[j] = fmaxf(mx[j], __shfl_xor(mx[j], 32));
    }
    if (quad == 0) {
        const float invc = 1.0f / (float)max(cnt, 1);
        const size_t base = (size_t)N_GRAPHS * 3 + (size_t)g * 256;
        #pragma unroll
        for (int j = 0; j < 8; ++j) {
            const float mean = sum[j] * invc;
            const float m2 = (cnt == 0) ? 0.f : mx[j];
            const int col = c * 8 + j;
            embs[wave][col] = mean;
            embs[wave][128 + col] = m2;
            if (md) {
                ((float*)outv)[base + col] = mean;
                ((float*)outv)[base + 128 + col] = m2;
            } else {
                ((u16*)outv)[base + col] = f2bf(mean);
                ((u16*)outv)[base + 128 + col] = f2bf(m2);
            }
        }
    }
    __syncthreads();
    // fc1: each wave computes its graph's 64 hidden units
    {
        const int tt = lane;
        float acc = md ? ((const float*)fcbv)[tt] : bf2f(((const u16*)fcbv)[tt]);
        if (md) {
            const float* w = (const float*)fcwv;
            #pragma unroll 8
            for (int k = 0; k < 256; ++k) acc += embs[wave][k] * w[k * 64 + tt];
        } else {
            const u16* w = (const u16*)fcwv;
            #pragma unroll 8
            for (int k = 0; k < 256; ++k) acc += embs[wave][k] * bf2f(w[k * 64 + tt]);
        }
        hs[wave][tt] = lrelu(acc);
    }
    __syncthreads();
    if (lane < 3) {
        float o = md ? ((const float*)fc2bv)[lane] : bf2f(((const u16*)fc2bv)[lane]);
        if (md) {
            const float* w = (const float*)fc2wv;
            #pragma unroll 8
            for (int j = 0; j < 64; ++j) o += hs[wave][j] * w[j * 3 + lane];
            ((float*)outv)[(size_t)g * 3 + lane] = o;
        } else {
            const u16* w = (const u16*)fc2wv;
            #pragma unroll 8
            for (int j = 0; j < 64; ++j) o += hs[wave][j] * bf2f(w[j * 3 + lane]);
            ((u16*)outv)[(size_t)g * 3 + lane] = f2bf(o);
        }
    }
}

// ---------------- launch ----------------
static inline size_t align256(size_t x) { return (x + 255) & ~(size_t)255; }

extern "C" void kernel_launch(void* const* d_in, const int* in_sizes, int n_in,
                              void* d_out, int out_size, void* d_ws, size_t ws_size,
                              hipStream_t stream) {
    (void)in_sizes; (void)n_in; (void)out_size; (void)ws_size;
    const void* x    = d_in[0];
    const void* W1a  = d_in[2];
    const void* W1b  = d_in[3];
    const void* b1   = d_in[4];
    const void* g1   = d_in[5];
    const void* be1  = d_in[6];
    const void* W2   = d_in[7];
    const void* b2   = d_in[8];
    const void* gn   = d_in[9];
    const void* bnb  = d_in[10];
    const void* fcw  = d_in[11];
    const void* fcb  = d_in[12];
    const void* fc2w = d_in[13];
    const void* fc2b = d_in[14];
    const int* ei    = (const int*)d_in[15];
    const int* batch = (const int*)d_in[16];

    char* p = (char*)d_ws;
    size_t off = 0;
    u16* zb = (u16*)(p + off); off += align256((size_t)N_NODES * HD * 2);
    u16* hb = (u16*)(p + off); off += align256((size_t)N_NODES * HD * 2);
    u16* xb = (u16*)(p + off); off += align256((size_t)N_NODES * 64 * 2);
    u16* wpack = (u16*)(p + off); off += align256((size_t)12 * HD * HD * 2);
    float* biasf = (float*)(p + off); off += align256((size_t)12 * HD * 4);
    int* row_ptr = (int*)(p + off); off += align256((size_t)(N_NODES + 1) * 4);
    int* col_idx = (int*)(p + off); off += align256((size_t)N_EDGES * 4);
    int* bsum = (int*)(p + off); off += align256((size_t)SB * 4);
    // contiguous zero region: cursor | statsAll | bar (one memset)
    size_t zero_begin = off;
    int* cursor = (int*)(p + off); off += align256((size_t)N_NODES * 4);
    float* statsAll = (float*)(p + off); off += align256((size_t)12 * NREP * 256 * 4);
    int* bar = (int*)(p + off); off += align256(64 * 4);
    size_t zero_len = off - zero_begin;
    int* mode = (int*)(p + off); off += align256(4);

    const int EB = (N_EDGES + 255) / 256;
    const int GBG = NTILES;  // 6250 (BM=16)

    detect_kernel<<<1, 256, 0, stream>>>((const u16*)x, mode);
    convx_kernel<<<GBG, 256, 0, stream>>>(x, mode, xb);

    hipMemsetAsync(p + zero_begin, 0, zero_len, stream);
    hist_kernel<<<EB, 256, 0, stream>>>(ei + N_EDGES, cursor);
    scan1_kernel<<<SB, 256, 0, stream>>>(cursor, bsum);
    scan2_kernel<<<1, 512, 0, stream>>>(bsum, row_ptr);
    scan3_kernel<<<SB, 256, 0, stream>>>(cursor, bsum, row_ptr, cursor);
    fill_kernel<<<EB, 256, 0, stream>>>(ei, ei + N_EDGES, cursor, col_idx);
    pack_w_kernel<<<96, 256, 0, stream>>>(W1a, W1b, W2, mode, wpack);
    pack_b_kernel<<<6, 256, 0, stream>>>(b1, b2, mode, biasf);

    int ncu = 0;
    int dev = 0;
    hipGetDevice(&dev);
    hipDeviceGetAttribute(&ncu, hipDeviceAttributeMultiprocessorCount, dev);
    const int cgrid = ncu * 4;  // 4 blocks/CU co-resident: 36KB LDS (4.44/CU) + launch_bounds(256,4)

    if (cgrid >= 893 && (long)cgrid * KTILES >= NTILES) {
        // persistent fused path: all 6 layers, t in LDS, software grid barriers
        layers_fused<<<cgrid, 256, 0, stream>>>(xb, zb, hb, row_ptr, col_idx, wpack, biasf,
                                                g1, be1, gn, bnb, mode, statsAll, bar);
        // final h = layer-5 output = hb
        poolfinal_kernel<<<N_GRAPHS / 4, 256, 0, stream>>>(hb, batch, mode, fcw, fcb, fc2w, fc2b, d_out);
    } else {
        // fallback: proven round-4 multi-kernel path
        u16* cur = zb;
        u16* oth = hb;
        for (int l = 0; l < NLAYERS; ++l) {
            float* statsA = statsAll + (size_t)l * NREP * 256;
            float* statsB = statsAll + (size_t)(6 + l) * NREP * 256;
            float* statsBprev = statsAll + (size_t)(6 + l - 1) * NREP * 256;
            if (l == 0) {
                gemm_gather0<<<GBG, 256, 0, stream>>>(xb, row_ptr, col_idx, wpack, biasf, cur, statsA);
            } else {
                gemm_gather<<<GBG, 256, 0, stream>>>(cur, row_ptr, col_idx,
                                                     wpack + (size_t)l * HD * HD,
                                                     biasf + (size_t)l * HD, statsBprev, gn, bnb,
                                                     (size_t)(l - 1) * HD, mode, oth, statsA);
                u16* t = cur; cur = oth; oth = t;
            }
            if (l < NLAYERS - 1) {
                gemm_mfma<1, 1><<<GBG, 256, 0, stream>>>(cur, wpack + (size_t)(6 + l) * HD * HD,
                                                         biasf + (size_t)(6 + l) * HD, statsA, g1, be1,
                                                         (size_t)l * HD, mode, cur, statsB);
            } else {
                gemm_mfma<1, 0><<<GBG, 256, 0, stream>>>(cur, wpack + (size_t)(6 + l) * HD * HD,
                                                         biasf + (size_t)(6 + l) * HD, statsA, g1, be1,
                                                         (size_t)l * HD, mode, cur, nullptr);
            }
        }
        poolfinal_kernel<<<N_GRAPHS / 4, 256, 0, stream>>>(cur, batch, mode, fcw, fcb, fc2w, fc2b, d_out);
    }
}

// Round 6
// 563.721 us; speedup vs baseline: 4.9549x; 4.9549x over previous
//
#include <hip/hip_runtime.h>
#include <stdint.h>

#define N_NODES 100000
#define N_EDGES 400000
#define N_GRAPHS 2000
#define C_IN 48
#define HD 128
#define NLAYERS 6
#define BN_EPS 1e-5f
#define NSLOPE 0.01f
#define SB 391   // ceil(N_NODES/256)
#define NREP 8   // stats replication factor
#define NTILES 6250

typedef uint16_t u16;
typedef uint32_t u32;
typedef short bf16x8 __attribute__((ext_vector_type(8)));
typedef float f32x4 __attribute__((ext_vector_type(4)));

__device__ __forceinline__ float bf2f_lo(u32 v) { return __uint_as_float(v << 16); }
__device__ __forceinline__ float bf2f_hi(u32 v) { return __uint_as_float(v & 0xffff0000u); }
__device__ __forceinline__ float bf2f(u16 h) { return __uint_as_float(((u32)h) << 16); }
__device__ __forceinline__ u16 f2bf(float f) {
    u32 u = __float_as_uint(f);
    u32 r = (u + 0x7fffu + ((u >> 16) & 1u)) >> 16;
    return (u16)r;
}
__device__ __forceinline__ u32 pack2(float a, float b) {
    return (u32)f2bf(a) | ((u32)f2bf(b) << 16);
}
// lrelu(x) = max(0.01x, x): 2 VALU, branchless, identical values for finite x.
__device__ __forceinline__ float lrelu(float v) { return fmaxf(v * NSLOPE, v); }

// dtype detection: mode=1 -> float inputs are fp32; mode=0 -> bf16.
__global__ __launch_bounds__(256) void detect_kernel(const u16* __restrict__ x, int* __restrict__ mode) {
    __shared__ int flag;
    if (threadIdx.x == 0) flag = 0;
    __syncthreads();
    int local = 0;
    for (int i = threadIdx.x; i < 16384; i += 256) {
        float a = fabsf(bf2f(x[i]));
        if (!(a < 1e4f)) local = 1;
    }
    if (local) flag = 1;
    __syncthreads();
    if (threadIdx.x == 0) mode[0] = flag;
}

// ---------------- x -> padded bf16 rows (one 128B cache line per row) ----------------
// xb[row][64] bf16: cols 0..47 = x, cols 48..63 = 0. Neighbor gather then reads exactly
// one line-aligned line per edge (halves layer-0 gather's logical miss bytes vs fp32).
__global__ __launch_bounds__(256) void convx_kernel(const void* __restrict__ xv, const int* __restrict__ mode,
                                                    u16* __restrict__ xb) {
    const int gid = blockIdx.x * 256 + threadIdx.x;  // 6250*256 == N_NODES*16 exactly
    const int row = gid >> 4, part = gid & 15;       // part = 4 cols
    u16 o0 = 0, o1 = 0, o2 = 0, o3 = 0;
    if (part < 12) {
        if (*mode) {
            const float4 v = *reinterpret_cast<const float4*>((const float*)xv + (size_t)row * C_IN + part * 4);
            o0 = f2bf(v.x); o1 = f2bf(v.y); o2 = f2bf(v.z); o3 = f2bf(v.w);
        } else {
            const ushort4 v = *reinterpret_cast<const ushort4*>((const u16*)xv + (size_t)row * C_IN + part * 4);
            o0 = v.x; o1 = v.y; o2 = v.z; o3 = v.w;
        }
    }
    ushort4 o; o.x = o0; o.y = o1; o.z = o2; o.w = o3;
    *reinterpret_cast<ushort4*>(xb + (size_t)row * 64 + part * 4) = o;
}

// ---------------- CSR build ----------------
__global__ __launch_bounds__(256) void hist_kernel(const int* __restrict__ dst, int* __restrict__ cnt) {
    int e = blockIdx.x * 256 + threadIdx.x;
    if (e < N_EDGES) atomicAdd(&cnt[dst[e]], 1);
}

__global__ __launch_bounds__(256) void scan1_kernel(const int* __restrict__ cnt, int* __restrict__ bsum) {
    __shared__ int s[256];
    const int t = threadIdx.x;
    const int i = blockIdx.x * 256 + t;
    s[t] = (i < N_NODES) ? cnt[i] : 0;
    __syncthreads();
    for (int d = 128; d > 0; d >>= 1) {
        if (t < d) s[t] += s[t + d];
        __syncthreads();
    }
    if (t == 0) bsum[blockIdx.x] = s[0];
}

__global__ __launch_bounds__(512) void scan2_kernel(int* __restrict__ bsum, int* __restrict__ row_ptr) {
    __shared__ int s[SB];
    const int t = threadIdx.x;
    if (t < SB) s[t] = bsum[t];
    __syncthreads();
    if (t == 0) {
        int run = 0;
        for (int b = 0; b < SB; ++b) { int v = s[b]; s[b] = run; run += v; }
        row_ptr[0] = 0;
    }
    __syncthreads();
    if (t < SB) bsum[t] = s[t];
}

// also writes cursor[i] = row_ptr[i] (exclusive prefix) -> drops the memcpy node
__global__ __launch_bounds__(256) void scan3_kernel(const int* __restrict__ cnt, const int* __restrict__ bsum,
                                                    int* __restrict__ row_ptr, int* __restrict__ cursor) {
    __shared__ int s[256];
    const int t = threadIdx.x;
    const int i = blockIdx.x * 256 + t;
    const int myc = (i < N_NODES) ? cnt[i] : 0;
    s[t] = myc;
    __syncthreads();
    if (t == 0) {
        int run = bsum[blockIdx.x];
        for (int j = 0; j < 256; ++j) { run += s[j]; s[j] = run; }
    }
    __syncthreads();
    if (i < N_NODES) {
        row_ptr[i + 1] = s[t];
        cursor[i] = s[t] - myc;
    }
}

__global__ __launch_bounds__(256) void fill_kernel(const int* __restrict__ src, const int* __restrict__ dst,
                                                   int* __restrict__ cursor, int* __restrict__ col_idx) {
    int e = blockIdx.x * 256 + threadIdx.x;
    if (e < N_EDGES) {
        int d = dst[e];
        int slot = atomicAdd(&cursor[d], 1);
        col_idx[slot] = src[e];
    }
}

// ---------------- weight pre-pack into MFMA B-fragment layout (bf16) ----------------
__global__ __launch_bounds__(256) void pack_w_kernel(const void* __restrict__ W1a, const void* __restrict__ W1b,
                                                     const void* __restrict__ W2, const int* __restrict__ mode,
                                                     u16* __restrict__ wpack) {
    const int t = blockIdx.x * 256 + threadIdx.x;  // 12*2048 = 24576
    if (t >= 24576) return;
    const int mat = t >> 11;
    const int r = t & 2047;
    const int l = r & 63;
    const int f = r >> 6;
    const int kb = f >> 3, nt = f & 7;
    const int k0 = kb * 32 + (l >> 4) * 8;
    const int n = nt * 16 + (l & 15);
    const int md = *mode;
    u16 vals[8];
    #pragma unroll
    for (int j = 0; j < 8; ++j) {
        const int k = k0 + j;
        float v;
        if (mat == 0) {
            v = (k < C_IN) ? (md ? ((const float*)W1a)[k * HD + n] : bf2f(((const u16*)W1a)[k * HD + n])) : 0.f;
        } else if (mat < 6) {
            const size_t o = (size_t)(mat - 1) * HD * HD + (size_t)k * HD + n;
            v = md ? ((const float*)W1b)[o] : bf2f(((const u16*)W1b)[o]);
        } else {
            const size_t o = (size_t)(mat - 6) * HD * HD + (size_t)k * HD + n;
            v = md ? ((const float*)W2)[o] : bf2f(((const u16*)W2)[o]);
        }
        vals[j] = f2bf(v);
    }
    uint4 o;
    o.x = (u32)vals[0] | ((u32)vals[1] << 16);
    o.y = (u32)vals[2] | ((u32)vals[3] << 16);
    o.z = (u32)vals[4] | ((u32)vals[5] << 16);
    o.w = (u32)vals[6] | ((u32)vals[7] << 16);
    *reinterpret_cast<uint4*>(wpack + (size_t)t * 8) = o;
}

// ---------------- bias pre-pack to f32 ----------------
__global__ __launch_bounds__(256) void pack_b_kernel(const void* __restrict__ b1, const void* __restrict__ b2,
                                                     const int* __restrict__ mode, float* __restrict__ biasf) {
    const int i = blockIdx.x * 256 + threadIdx.x;  // 12*128
    if (i >= 12 * HD) return;
    const int mat = i >> 7, c = i & 127;
    const int md = *mode;
    float v;
    if (mat < 6) v = md ? ((const float*)b1)[mat * HD + c] : bf2f(((const u16*)b1)[mat * HD + c]);
    else         v = md ? ((const float*)b2)[(mat - 6) * HD + c] : bf2f(((const u16*)b2)[(mat - 6) * HD + c]);
    biasf[i] = v;
}

// ---- shared helper: compute BN coef[256]={A,B} in LDS from replicated raw stats ----
__device__ __forceinline__ void coef_to_lds(float* coefs, const float* __restrict__ instats,
                                            const void* __restrict__ gammav, const void* __restrict__ betav,
                                            size_t gelem, int md, int tid) {
    if (tid < 128) {
        float sm = 0.f, sq = 0.f;
        #pragma unroll
        for (int rep = 0; rep < NREP; ++rep) {
            sm += instats[rep * 256 + tid];
            sq += instats[rep * 256 + 128 + tid];
        }
        const float inv_n = 1.0f / (float)N_NODES;
        const float mean = sm * inv_n;
        const float var = fmaxf(sq * inv_n - mean * mean, 0.f);
        const float rs = rsqrtf(var + BN_EPS);
        const float g  = md ? ((const float*)gammav)[gelem + tid] : bf2f(((const u16*)gammav)[gelem + tid]);
        const float be = md ? ((const float*)betav)[gelem + tid]  : bf2f(((const u16*)betav)[gelem + tid]);
        const float A = g * rs;
        coefs[tid] = A;
        coefs[128 + tid] = be - A * mean;
    }
}

// ---------------- plain MFMA GEMM — BM=16, SAME GRID as gather kernels ----------------
// XCD alignment: block g covers rows [16g,16g+16) in EVERY per-node kernel, so with
// round-robin workgroup->XCD dispatch the t-write (gather block g), t-read (this block g),
// h'-write (this block g) and next-layer self-read (gather block g) all land on XCD g%8
// -> the sequential round-trip traffic becomes per-XCD L2 hits (3.2MB slice < 4MB L2).
// NOTE (round-5 lesson): do NOT replace these kernel boundaries with software grid
// barriers — agent-scope fences cost a full L2 writeback+invalidate PER BLOCK on gfx950.
// TRANS: BN coefs computed in-block, applied while staging. IN-PLACE SAFE (out == A).
template <int TRANS, int STATS>
__global__ __launch_bounds__(256) void gemm_mfma(const u16* A, const u16* __restrict__ wp,
                                                 const float* __restrict__ biasf,
                                                 const float* __restrict__ instats,
                                                 const void* __restrict__ gammav, const void* __restrict__ betav,
                                                 size_t gelem, const int* __restrict__ mode,
                                                 u16* out, float* __restrict__ stats) {
    __shared__ u16 Asm[16][136];
    __shared__ float sred[128];
    __shared__ float sqred[128];
    __shared__ float coefs[256];
    const int tid = threadIdx.x;
    const int m0 = blockIdx.x * 16;
    const int rrow = tid >> 4;   // 0..15 = row
    const int seg = tid & 15;

    if (TRANS) {
        coef_to_lds(coefs, instats, gammav, betav, gelem, *mode, tid);
        __syncthreads();
    }

    {
        // 6250*16 == N_NODES exactly: no row guard needed.
        const int gm = m0 + rrow;
        uint4 o = *reinterpret_cast<const uint4*>((const char*)A + (((u32)gm << 8) + ((u32)seg << 4)));
        if (TRANS) {
            float cA[8], cB[8];
            #pragma unroll
            for (int j = 0; j < 8; ++j) {
                cA[j] = coefs[seg * 8 + j];
                cB[j] = coefs[128 + seg * 8 + j];
            }
            u32 w[4] = {o.x, o.y, o.z, o.w};
            #pragma unroll
            for (int p = 0; p < 4; ++p) {
                const float lo = lrelu(cA[2 * p] * bf2f_lo(w[p]) + cB[2 * p]);
                const float hi = lrelu(cA[2 * p + 1] * bf2f_hi(w[p]) + cB[2 * p + 1]);
                w[p] = pack2(lo, hi);
            }
            o.x = w[0]; o.y = w[1]; o.z = w[2]; o.w = w[3];
        }
        *reinterpret_cast<uint4*>(&Asm[rrow][seg * 8]) = o;
    }
    __syncthreads();

    // MFMA: wave w covers cols w*32..+32 of the 16-row tile
    const int wave = tid >> 6, lane = tid & 63;
    const int quad = lane >> 4, lx = lane & 15;
    f32x4 acc[2] = {};
    #pragma unroll
    for (int kb = 0; kb < 4; ++kb) {
        bf16x8 bfr[2];
        #pragma unroll
        for (int nt = 0; nt < 2; ++nt)
            bfr[nt] = *reinterpret_cast<const bf16x8*>(wp + (((size_t)(kb * 8 + wave * 2 + nt) * 64 + lane) << 3));
        const bf16x8 af = *reinterpret_cast<const bf16x8*>(&Asm[lx][kb * 32 + quad * 8]);
        #pragma unroll
        for (int nt = 0; nt < 2; ++nt)
            acc[nt] = __builtin_amdgcn_mfma_f32_16x16x32_bf16(af, bfr[nt], acc[nt], 0, 0, 0);
    }

    #pragma unroll
    for (int nt = 0; nt < 2; ++nt) {
        const int n = wave * 32 + nt * 16 + lx;
        const float bj = biasf[n];
        float s = 0.f, q = 0.f;
        #pragma unroll
        for (int r = 0; r < 4; ++r) {
            const int m = m0 + quad * 4 + r;
            const float v = acc[nt][r] + bj;
            out[(size_t)m * HD + n] = f2bf(v);
            if (STATS) { s += v; q += v * v; }
        }
        if (STATS) {
            s += __shfl_xor(s, 16); s += __shfl_xor(s, 32);
            q += __shfl_xor(q, 16); q += __shfl_xor(q, 32);
            if (quad == 0) { sred[n] = s; sqred[n] = q; }  // cols partitioned across waves: no race
        }
    }
    if (STATS) {
        __syncthreads();
        float* sdst = stats + (size_t)(blockIdx.x & (NREP - 1)) * 256;
        if (tid < 128) atomicAdd(&sdst[tid], sred[tid]);
        else if (tid < 256) atomicAdd(&sdst[tid], sqred[tid - 128]);
    }
}

// ---------------- FUSED gather+BN+lrelu GEMM — BM=16 (6250 blocks) ----------------
// One node per staging thread; wave w covers cols w*32..+32.
// NOT in-place. STATS on. Block g <-> rows [16g,16g+16) (XCD-aligned with gemm_mfma).
__global__ __launch_bounds__(256) void gemm_gather(const u16* __restrict__ U, const int* __restrict__ row_ptr,
                                                   const int* __restrict__ col_idx, const u16* __restrict__ wp,
                                                   const float* __restrict__ biasf,
                                                   const float* __restrict__ instats,
                                                   const void* __restrict__ gammav, const void* __restrict__ betav,
                                                   size_t gelem, const int* __restrict__ mode,
                                                   u16* __restrict__ out, float* __restrict__ stats) {
    __shared__ u16 Asm[16][136];
    __shared__ float sred[128];
    __shared__ float sqred[128];
    __shared__ float coefs[256];
    const int tid = threadIdx.x;
    const int m0 = blockIdx.x * 16;
    const int rrow = tid >> 4;   // 0..15 = row
    const int seg = tid & 15;

    coef_to_lds(coefs, instats, gammav, betav, gelem, *mode, tid);
    __syncthreads();

    {
        float cA[8], cB[8];
        #pragma unroll
        for (int j = 0; j < 8; ++j) {
            cA[j] = coefs[seg * 8 + j];
            cB[j] = coefs[128 + seg * 8 + j];
        }
        const int gm = m0 + rrow;
        const u32 soff = (u32)seg << 4;
        float a[8];
        #pragma unroll
        for (int j = 0; j < 8; ++j) a[j] = 0.f;
        {
            // self row
            {
                const uint4 v = *reinterpret_cast<const uint4*>((const char*)U + (((u32)gm << 8) + soff));
                const u32 w[4] = {v.x, v.y, v.z, v.w};
                #pragma unroll
                for (int p = 0; p < 4; ++p) {
                    a[2 * p]     = lrelu(cA[2 * p] * bf2f_lo(w[p]) + cB[2 * p]);
                    a[2 * p + 1] = lrelu(cA[2 * p + 1] * bf2f_hi(w[p]) + cB[2 * p + 1]);
                }
            }
            const int s = row_ptr[gm];
            const int deg = row_ptr[gm + 1] - s;
            for (int t = 0; t < deg; t += 2) {
                const int id0 = col_idx[s + t];
                const bool h1 = (t + 1) < deg;
                const int id1 = h1 ? col_idx[s + t + 1] : 0;
                const uint4 r0 = *reinterpret_cast<const uint4*>((const char*)U + (((u32)id0 << 8) + soff));
                uint4 r1; r1.x = r1.y = r1.z = r1.w = 0;
                if (h1) r1 = *reinterpret_cast<const uint4*>((const char*)U + (((u32)id1 << 8) + soff));
                const u32 w0[4] = {r0.x, r0.y, r0.z, r0.w};
                const u32 w1[4] = {r1.x, r1.y, r1.z, r1.w};
                #pragma unroll
                for (int p = 0; p < 4; ++p) {
                    a[2 * p]     += lrelu(cA[2 * p] * bf2f_lo(w0[p]) + cB[2 * p]);
                    a[2 * p + 1] += lrelu(cA[2 * p + 1] * bf2f_hi(w0[p]) + cB[2 * p + 1]);
                    if (h1) {
                        a[2 * p]     += lrelu(cA[2 * p] * bf2f_lo(w1[p]) + cB[2 * p]);
                        a[2 * p + 1] += lrelu(cA[2 * p + 1] * bf2f_hi(w1[p]) + cB[2 * p + 1]);
                    }
                }
            }
        }
        uint4 o;
        o.x = pack2(a[0], a[1]); o.y = pack2(a[2], a[3]);
        o.z = pack2(a[4], a[5]); o.w = pack2(a[6], a[7]);
        *reinterpret_cast<uint4*>(&Asm[rrow][seg * 8]) = o;
    }
    __syncthreads();

    // MFMA: wave w covers cols w*32..+32 of the 16-row tile
    const int wave = tid >> 6, lane = tid & 63;
    const int quad = lane >> 4, lx = lane & 15;
    f32x4 acc[2] = {};
    #pragma unroll
    for (int kb = 0; kb < 4; ++kb) {
        bf16x8 bfr[2];
        #pragma unroll
        for (int nt = 0; nt < 2; ++nt)
            bfr[nt] = *reinterpret_cast<const bf16x8*>(wp + (((size_t)(kb * 8 + wave * 2 + nt) * 64 + lane) << 3));
        const bf16x8 af = *reinterpret_cast<const bf16x8*>(&Asm[lx][kb * 32 + quad * 8]);
        #pragma unroll
        for (int nt = 0; nt < 2; ++nt)
            acc[nt] = __builtin_amdgcn_mfma_f32_16x16x32_bf16(af, bfr[nt], acc[nt], 0, 0, 0);
    }

    #pragma unroll
    for (int nt = 0; nt < 2; ++nt) {
        const int n = wave * 32 + nt * 16 + lx;
        const float bj = biasf[n];
        float s = 0.f, q = 0.f;
        #pragma unroll
        for (int r = 0; r < 4; ++r) {
            const int m = m0 + quad * 4 + r;
            const float v = acc[nt][r] + bj;
            out[(size_t)m * HD + n] = f2bf(v);
            s += v; q += v * v;
        }
        s += __shfl_xor(s, 16); s += __shfl_xor(s, 32);
        q += __shfl_xor(q, 16); q += __shfl_xor(q, 32);
        if (quad == 0) { sred[n] = s; sqred[n] = q; }  // cols partitioned across waves: no race
    }
    __syncthreads();
    float* sdst = stats + (size_t)(blockIdx.x & (NREP - 1)) * 256;
    if (tid < 128) atomicAdd(&sdst[tid], sred[tid]);
    else if (tid < 256) atomicAdd(&sdst[tid], sqred[tid - 128]);
}

// ---------------- FUSED layer-0: gather over padded-bf16 xb (one line/row) + GEMM — BM=16 ----------------
__global__ __launch_bounds__(256) void gemm_gather0(const u16* __restrict__ xb, const int* __restrict__ row_ptr,
                                                    const int* __restrict__ col_idx, const u16* __restrict__ wp,
                                                    const float* __restrict__ biasf,
                                                    u16* __restrict__ out, float* __restrict__ stats) {
    __shared__ u16 Asm[16][136];
    __shared__ float sred[128];
    __shared__ float sqred[128];
    const int tid = threadIdx.x;
    const int m0 = blockIdx.x * 16;
    const int rrow = tid >> 4;
    const int seg = tid & 15;          // segs 0..7 carry data (64 padded cols), 8..15 zero
    const bool act = seg < 8;
    {
        const int gm = m0 + rrow;
        float a[8];
        #pragma unroll
        for (int j = 0; j < 8; ++j) a[j] = 0.f;
        if (act) {
            const u32 soff = (u32)seg << 4;
            // self row (xb rows are 128B: row<<7)
            {
                const uint4 v = *reinterpret_cast<const uint4*>((const char*)xb + (((u32)gm << 7) + soff));
                const u32 w[4] = {v.x, v.y, v.z, v.w};
                #pragma unroll
                for (int p = 0; p < 4; ++p) { a[2 * p] = bf2f_lo(w[p]); a[2 * p + 1] = bf2f_hi(w[p]); }
            }
            const int s = row_ptr[gm];
            const int deg = row_ptr[gm + 1] - s;
            for (int t = 0; t < deg; t += 2) {
                const int id0 = col_idx[s + t];
                const bool h1 = (t + 1) < deg;
                const int id1 = h1 ? col_idx[s + t + 1] : 0;
                const uint4 r0 = *reinterpret_cast<const uint4*>((const char*)xb + (((u32)id0 << 7) + soff));
                uint4 r1; r1.x = r1.y = r1.z = r1.w = 0;
                if (h1) r1 = *reinterpret_cast<const uint4*>((const char*)xb + (((u32)id1 << 7) + soff));
                const u32 w0[4] = {r0.x, r0.y, r0.z, r0.w};
                const u32 w1[4] = {r1.x, r1.y, r1.z, r1.w};
                #pragma unroll
                for (int p = 0; p < 4; ++p) {
                    a[2 * p]     += bf2f_lo(w0[p]) + bf2f_lo(w1[p]);
                    a[2 * p + 1] += bf2f_hi(w0[p]) + bf2f_hi(w1[p]);
                }
            }
        }
        uint4 o;
        o.x = pack2(a[0], a[1]); o.y = pack2(a[2], a[3]);
        o.z = pack2(a[4], a[5]); o.w = pack2(a[6], a[7]);
        *reinterpret_cast<uint4*>(&Asm[rrow][seg * 8]) = o;
    }
    __syncthreads();

    const int wave = tid >> 6, lane = tid & 63;
    const int quad = lane >> 4, lx = lane & 15;
    f32x4 acc[2] = {};
    // kb 2..3 (K=64..127) are all-zero in both A (pad) and W1a (K>=48 zeroed): skip.
    #pragma unroll
    for (int kb = 0; kb < 2; ++kb) {
        bf16x8 bfr[2];
        #pragma unroll
        for (int nt = 0; nt < 2; ++nt)
            bfr[nt] = *reinterpret_cast<const bf16x8*>(wp + (((size_t)(kb * 8 + wave * 2 + nt) * 64 + lane) << 3));
        const bf16x8 af = *reinterpret_cast<const bf16x8*>(&Asm[lx][kb * 32 + quad * 8]);
        #pragma unroll
        for (int nt = 0; nt < 2; ++nt)
            acc[nt] = __builtin_amdgcn_mfma_f32_16x16x32_bf16(af, bfr[nt], acc[nt], 0, 0, 0);
    }

    #pragma unroll
    for (int nt = 0; nt < 2; ++nt) {
        const int n = wave * 32 + nt * 16 + lx;
        const float bj = biasf[n];
        float s = 0.f, q = 0.f;
        #pragma unroll
        for (int r = 0; r < 4; ++r) {
            const int m = m0 + quad * 4 + r;
            const float v = acc[nt][r] + bj;
            out[(size_t)m * HD + n] = f2bf(v);
            s += v; q += v * v;
        }
        s += __shfl_xor(s, 16); s += __shfl_xor(s, 32);
        q += __shfl_xor(q, 16); q += __shfl_xor(q, 32);
        if (quad == 0) { sred[n] = s; sqred[n] = q; }
    }
    __syncthreads();
    float* sdst = stats + (size_t)(blockIdx.x & (NREP - 1)) * 256;
    if (tid < 128) atomicAdd(&sdst[tid], sred[tid]);
    else if (tid < 256) atomicAdd(&sdst[tid], sqred[tid - 128]);
}

// ---------------- merged pooling + classifier head: 500 blocks, wave per graph ----------------
__global__ __launch_bounds__(256) void poolfinal_kernel(const u16* __restrict__ hf, const int* __restrict__ batch,
                                                        const int* __restrict__ mode,
                                                        const void* __restrict__ fcwv, const void* __restrict__ fcbv,
                                                        const void* __restrict__ fc2wv, const void* __restrict__ fc2bv,
                                                        void* __restrict__ outv) {
    __shared__ float embs[4][256];
    __shared__ float hs[4][64];
    const int wave = threadIdx.x >> 6, lane = threadIdx.x & 63;
    const int g = blockIdx.x * 4 + wave;   // 500*4 == N_GRAPHS exactly
    const int md = *mode;
    const int quad = lane >> 4, c = lane & 15;
    int lo = 0, hi = N_NODES;
    while (lo < hi) { int m = (lo + hi) >> 1; if (batch[m] < g) lo = m + 1; else hi = m; }
    const int s = lo;
    hi = N_NODES;
    while (lo < hi) { int m = (lo + hi) >> 1; if (batch[m] < g + 1) lo = m + 1; else hi = m; }
    const int e = lo;
    const int cnt = e - s;
    float sum[8], mx[8];
    #pragma unroll
    for (int j = 0; j < 8; ++j) { sum[j] = 0.f; mx[j] = -INFINITY; }
    for (int n = s + quad; n < e; n += 4) {
        const uint4 v = *reinterpret_cast<const uint4*>(hf + (size_t)n * HD + c * 8);
        const u32 w[4] = {v.x, v.y, v.z, v.w};
        #pragma unroll
        for (int p = 0; p < 4; ++p) {
            const float f0 = bf2f_lo(w[p]), f1 = bf2f_hi(w[p]);
            sum[2 * p] += f0; sum[2 * p + 1] += f1;
            mx[2 * p] = fmaxf(mx[2 * p], f0); mx[2 * p + 1] = fmaxf(mx[2 * p + 1], f1);
        }
    }
    #pragma unroll
    for (int j = 0; j < 8; ++j) {
        sum[j] += __shfl_xor(sum[j], 16); sum[j] += __shfl_xor(sum[j], 32);
        mx[j] = fmaxf(mx[j], __shfl_xor(mx[j], 16));
        mx[j] = fmaxf(mx[j], __shfl_xor(mx[j], 32));
    }
    if (quad == 0) {
        const float invc = 1.0f / (float)max(cnt, 1);
        const size_t base = (size_t)N_GRAPHS * 3 + (size_t)g * 256;
        #pragma unroll
        for (int j = 0; j < 8; ++j) {
            const float mean = sum[j] * invc;
            const float m2 = (cnt == 0) ? 0.f : mx[j];
            const int col = c * 8 + j;
            embs[wave][col] = mean;
            embs[wave][128 + col] = m2;
            if (md) {
                ((float*)outv)[base + col] = mean;
                ((float*)outv)[base + 128 + col] = m2;
            } else {
                ((u16*)outv)[base + col] = f2bf(mean);
                ((u16*)outv)[base + 128 + col] = f2bf(m2);
            }
        }
    }
    __syncthreads();
    // fc1: each wave computes its graph's 64 hidden units
    {
        const int tt = lane;
        float acc = md ? ((const float*)fcbv)[tt] : bf2f(((const u16*)fcbv)[tt]);
        if (md) {
            const float* w = (const float*)fcwv;
            #pragma unroll 8
            for (int k = 0; k < 256; ++k) acc += embs[wave][k] * w[k * 64 + tt];
        } else {
            const u16* w = (const u16*)fcwv;
            #pragma unroll 8
            for (int k = 0; k < 256; ++k) acc += embs[wave][k] * bf2f(w[k * 64 + tt]);
        }
        hs[wave][tt] = lrelu(acc);
    }
    __syncthreads();
    if (lane < 3) {
        float o = md ? ((const float*)fc2bv)[lane] : bf2f(((const u16*)fc2bv)[lane]);
        if (md) {
            const float* w = (const float*)fc2wv;
            #pragma unroll 8
            for (int j = 0; j < 64; ++j) o += hs[wave][j] * w[j * 3 + lane];
            ((float*)outv)[(size_t)g * 3 + lane] = o;
        } else {
            const u16* w = (const u16*)fc2wv;
            #pragma unroll 8
            for (int j = 0; j < 64; ++j) o += hs[wave][j] * bf2f(w[j * 3 + lane]);
            ((u16*)outv)[(size_t)g * 3 + lane] = f2bf(o);
        }
    }
}

// ---------------- launch ----------------
static inline size_t align256(size_t x) { return (x + 255) & ~(size_t)255; }

extern "C" void kernel_launch(void* const* d_in, const int* in_sizes, int n_in,
                              void* d_out, int out_size, void* d_ws, size_t ws_size,
                              hipStream_t stream) {
    (void)in_sizes; (void)n_in; (void)out_size; (void)ws_size;
    const void* x    = d_in[0];
    const void* W1a  = d_in[2];
    const void* W1b  = d_in[3];
    const void* b1   = d_in[4];
    const void* g1   = d_in[5];
    const void* be1  = d_in[6];
    const void* W2   = d_in[7];
    const void* b2   = d_in[8];
    const void* gn   = d_in[9];
    const void* bnb  = d_in[10];
    const void* fcw  = d_in[11];
    const void* fcb  = d_in[12];
    const void* fc2w = d_in[13];
    const void* fc2b = d_in[14];
    const int* ei    = (const int*)d_in[15];
    const int* batch = (const int*)d_in[16];

    char* p = (char*)d_ws;
    size_t off = 0;
    u16* zb = (u16*)(p + off); off += align256((size_t)N_NODES * HD * 2);
    u16* hb = (u16*)(p + off); off += align256((size_t)N_NODES * HD * 2);
    u16* xb = (u16*)(p + off); off += align256((size_t)N_NODES * 64 * 2);
    u16* wpack = (u16*)(p + off); off += align256((size_t)12 * HD * HD * 2);
    float* biasf = (float*)(p + off); off += align256((size_t)12 * HD * 4);
    int* row_ptr = (int*)(p + off); off += align256((size_t)(N_NODES + 1) * 4);
    int* col_idx = (int*)(p + off); off += align256((size_t)N_EDGES * 4);
    int* bsum = (int*)(p + off); off += align256((size_t)SB * 4);
    // contiguous zero region: cursor | statsAll (one memset)
    size_t zero_begin = off;
    int* cursor = (int*)(p + off); off += align256((size_t)N_NODES * 4);
    float* statsAll = (float*)(p + off); off += align256((size_t)12 * NREP * 256 * 4);
    size_t zero_len = off - zero_begin;
    int* mode = (int*)(p + off); off += align256(4);

    const int EB = (N_EDGES + 255) / 256;
    const int GBG = NTILES;  // 6250 (BM=16, shared by ALL per-node kernels)

    detect_kernel<<<1, 256, 0, stream>>>((const u16*)x, mode);
    convx_kernel<<<GBG, 256, 0, stream>>>(x, mode, xb);

    hipMemsetAsync(p + zero_begin, 0, zero_len, stream);
    hist_kernel<<<EB, 256, 0, stream>>>(ei + N_EDGES, cursor);
    scan1_kernel<<<SB, 256, 0, stream>>>(cursor, bsum);
    scan2_kernel<<<1, 512, 0, stream>>>(bsum, row_ptr);
    scan3_kernel<<<SB, 256, 0, stream>>>(cursor, bsum, row_ptr, cursor);
    fill_kernel<<<EB, 256, 0, stream>>>(ei, ei + N_EDGES, cursor, col_idx);
    pack_w_kernel<<<96, 256, 0, stream>>>(W1a, W1b, W2, mode, wpack);
    pack_b_kernel<<<6, 256, 0, stream>>>(b1, b2, mode, biasf);

    u16* cur = zb;
    u16* oth = hb;
    for (int l = 0; l < NLAYERS; ++l) {
        float* statsA = statsAll + (size_t)l * NREP * 256;
        float* statsB = statsAll + (size_t)(6 + l) * NREP * 256;
        float* statsBprev = statsAll + (size_t)(6 + l - 1) * NREP * 256;
        if (l == 0) {
            // fused gather(xb) + gemm1 (no BN on input): xb -> cur
            gemm_gather0<<<GBG, 256, 0, stream>>>(xb, row_ptr, col_idx, wpack, biasf, cur, statsA);
        } else {
            // fused gather+BN(outer,l-1)+lrelu + gemm1: cur -> oth (not in-place)
            gemm_gather<<<GBG, 256, 0, stream>>>(cur, row_ptr, col_idx,
                                                 wpack + (size_t)l * HD * HD,
                                                 biasf + (size_t)l * HD, statsBprev, gn, bnb,
                                                 (size_t)(l - 1) * HD, mode, oth, statsA);
            u16* t = cur; cur = oth; oth = t;
        }
        if (l < NLAYERS - 1) {
            gemm_mfma<1, 1><<<GBG, 256, 0, stream>>>(cur, wpack + (size_t)(6 + l) * HD * HD,
                                                     biasf + (size_t)(6 + l) * HD, statsA, g1, be1,
                                                     (size_t)l * HD, mode, cur, statsB);
        } else {
            gemm_mfma<1, 0><<<GBG, 256, 0, stream>>>(cur, wpack + (size_t)(6 + l) * HD * HD,
                                                     biasf + (size_t)(6 + l) * HD, statsA, g1, be1,
                                                     (size_t)l * HD, mode, cur, nullptr);
        }
    }

    poolfinal_kernel<<<N_GRAPHS / 4, 256, 0, stream>>>(cur, batch, mode, fcw, fcb, fc2w, fc2b, d_out);
}